// Round 8
// baseline (692.858 us; speedup 1.0000x reference)
//
#include <hip/hip_runtime.h>

// Problem constants
#define NN 50000      // nodes
#define NE 800000     // edges
#define MP 50176      // padded rows = 196*256
#define GG 64         // graphs
#define HD 512        // hidden/feature dim
#define K2 1024       // fused K (agg | self)
#define SCAN_BLKS 196 // ceil(50000/256)

typedef __attribute__((ext_vector_type(8))) short bf16x8;
typedef __attribute__((ext_vector_type(4))) float f32x4;

__device__ __forceinline__ unsigned short f2bf(float f) {
  unsigned u = __builtin_bit_cast(unsigned, f);
  u += 0x7fffu + ((u >> 16) & 1u);
  return (unsigned short)(u >> 16);
}
__device__ __forceinline__ float bf2f(unsigned short h) {
  unsigned u = ((unsigned)h) << 16;
  return __builtin_bit_cast(float, u);
}

__device__ __forceinline__ void g2l16(const void* g, void* l) {
  __builtin_amdgcn_global_load_lds(
      (const __attribute__((address_space(1))) unsigned int*)g,
      (__attribute__((address_space(3))) unsigned int*)l, 16, 0, 0);
}

// ---------------- fused prologue: weight transpose x2 + x->bf16 pad + degree histogram
__global__ __launch_bounds__(256) void prep_kernel(
    const float* __restrict__ x, unsigned short* __restrict__ xb,
    const float* __restrict__ Wr0, const float* __restrict__ Ws0, unsigned short* __restrict__ Wt0,
    const float* __restrict__ Wr1, const float* __restrict__ Ws1, unsigned short* __restrict__ Wt1,
    const int* __restrict__ ei, int* __restrict__ deg) {
  int b = blockIdx.x, t = threadIdx.x;
  if (b < 256) {
    // 64x64 transpose tile: W[k][n] (fp32) -> Wt[n][half*512+k] (bf16)
    __shared__ float sh[64][65];
    int layer = b >> 7, tl = b & 127;
    int tn = tl >> 4, tk = tl & 15;
    int half = tk >> 3;
    int kw = (tk & 7) * 64, n0 = tn * 64;
    const float* W = layer ? (half ? Ws1 : Wr1) : (half ? Ws0 : Wr0);
    unsigned short* Wt = layer ? Wt1 : Wt0;
    int nn = t & 63;
    int kb = t >> 6;
#pragma unroll
    for (int i = 0; i < 16; i++) {
      int kk = kb + i * 4;
      sh[kk][nn] = W[(size_t)(kw + kk) * HD + n0 + nn];
    }
    __syncthreads();
    int kk2 = t & 63;
#pragma unroll
    for (int i = 0; i < 16; i++) {
      int nn2 = kb + i * 4;
      Wt[(size_t)(n0 + nn2) * K2 + half * HD + kw + kk2] = f2bf(sh[kk2][nn2]);
    }
  } else if (b < 2304) {
    const long long total4 = (long long)MP * HD / 4;
    for (long long i = (long long)(b - 256) * 256 + t; i < total4; i += 2048LL * 256) {
      int r = (int)((i * 4) >> 9);
      float4 v = make_float4(0.f, 0.f, 0.f, 0.f);
      if (r < NN) v = ((const float4*)x)[i];
      ushort4 o;
      o.x = f2bf(v.x); o.y = f2bf(v.y); o.z = f2bf(v.z); o.w = f2bf(v.w);
      ((ushort4*)xb)[i] = o;
    }
  } else {
    for (int i = (b - 2304) * 256 + t; i < NE; i += 512 * 256) {
      atomicAdd(&deg[ei[NE + i]], 1);
    }
  }
}

// ---------------- CSR scan (3-phase) + fill
__global__ __launch_bounds__(256) void scan1_kernel(const int* __restrict__ deg,
                                                    int* __restrict__ tmp,
                                                    int* __restrict__ bsum) {
  __shared__ int sh[256];
  int t = threadIdx.x;
  int i = blockIdx.x * 256 + t;
  int v = (i < NN) ? deg[i] : 0;
  sh[t] = v;
  __syncthreads();
#pragma unroll
  for (int off = 1; off < 256; off <<= 1) {
    int u = (t >= off) ? sh[t - off] : 0;
    __syncthreads();
    sh[t] += u;
    __syncthreads();
  }
  if (i < NN) tmp[i] = sh[t] - v;
  if (t == 255) bsum[blockIdx.x] = sh[255];
}

__global__ __launch_bounds__(256) void scan2_kernel(int* __restrict__ bsum,
                                                    int* __restrict__ row_ptr) {
  __shared__ int sh[256];
  int t = threadIdx.x;
  int v = (t < SCAN_BLKS) ? bsum[t] : 0;
  sh[t] = v;
  __syncthreads();
#pragma unroll
  for (int off = 1; off < 256; off <<= 1) {
    int u = (t >= off) ? sh[t - off] : 0;
    __syncthreads();
    sh[t] += u;
    __syncthreads();
  }
  if (t < SCAN_BLKS) bsum[t] = sh[t] - v;
  if (t == 255) row_ptr[NN] = sh[255];
}

__global__ __launch_bounds__(256) void scan3_kernel(const int* __restrict__ tmp,
                                                    const int* __restrict__ bsum,
                                                    int* __restrict__ row_ptr,
                                                    int* __restrict__ cursor) {
  int i = blockIdx.x * 256 + threadIdx.x;
  if (i < NN) {
    int r = tmp[i] + bsum[blockIdx.x];
    row_ptr[i] = r;
    cursor[i] = r;
  }
}

__global__ void fill_kernel(const int* __restrict__ ei, int* __restrict__ cursor,
                            int* __restrict__ col) {
  int i = blockIdx.x * 256 + threadIdx.x;
  if (i < NE) {
    int d = ei[NE + i];
    int p = atomicAdd(&cursor[d], 1);
    col[p] = ei[i];
  }
}

// ---------------- gather aggregation (R6 version, near structural floor)
#define ACC8(v, a)                                        \
  a[0] += bf2f((unsigned short)((v).x & 0xffff));         \
  a[1] += bf2f((unsigned short)((v).x >> 16));            \
  a[2] += bf2f((unsigned short)((v).y & 0xffff));         \
  a[3] += bf2f((unsigned short)((v).y >> 16));            \
  a[4] += bf2f((unsigned short)((v).z & 0xffff));         \
  a[5] += bf2f((unsigned short)((v).z >> 16));            \
  a[6] += bf2f((unsigned short)((v).w & 0xffff));         \
  a[7] += bf2f((unsigned short)((v).w >> 16));

__global__ __launch_bounds__(256) void gather_kernel(const unsigned short* __restrict__ X,
                                                     const int* __restrict__ row_ptr,
                                                     const int* __restrict__ col,
                                                     unsigned short* __restrict__ out) {
  int w = (blockIdx.x * 256 + threadIdx.x) >> 6;  // wave id = output row
  int lane = threadIdx.x & 63;
  if (w >= MP) return;
  float a[8] = {0.f, 0.f, 0.f, 0.f, 0.f, 0.f, 0.f, 0.f};
  if (w < NN) {
    int r0 = row_ptr[w], r1 = row_ptr[w + 1];
    const unsigned short* Xl = X + lane * 8;
    for (int base = r0; base < r1; base += 64) {
      int idx = base + lane;
      int myc = (idx < r1) ? col[idx] : 0;
      int cnt = min(64, r1 - base);
      int j = 0;
      for (; j + 8 <= cnt; j += 8) {
        int c0 = __shfl(myc, j + 0), c1 = __shfl(myc, j + 1);
        int c2 = __shfl(myc, j + 2), c3 = __shfl(myc, j + 3);
        int c4 = __shfl(myc, j + 4), c5 = __shfl(myc, j + 5);
        int c6 = __shfl(myc, j + 6), c7 = __shfl(myc, j + 7);
        uint4 v0 = *(const uint4*)(Xl + (size_t)c0 * HD);
        uint4 v1 = *(const uint4*)(Xl + (size_t)c1 * HD);
        uint4 v2 = *(const uint4*)(Xl + (size_t)c2 * HD);
        uint4 v3 = *(const uint4*)(Xl + (size_t)c3 * HD);
        uint4 v4 = *(const uint4*)(Xl + (size_t)c4 * HD);
        uint4 v5 = *(const uint4*)(Xl + (size_t)c5 * HD);
        uint4 v6 = *(const uint4*)(Xl + (size_t)c6 * HD);
        uint4 v7 = *(const uint4*)(Xl + (size_t)c7 * HD);
        ACC8(v0, a) ACC8(v1, a) ACC8(v2, a) ACC8(v3, a)
        ACC8(v4, a) ACC8(v5, a) ACC8(v6, a) ACC8(v7, a)
      }
      for (; j < cnt; j++) {
        int c = __shfl(myc, j);
        uint4 v = *(const uint4*)(Xl + (size_t)c * HD);
        ACC8(v, a)
      }
    }
  }
  uint4 o;
  o.x = ((unsigned)f2bf(a[1]) << 16) | f2bf(a[0]);
  o.y = ((unsigned)f2bf(a[3]) << 16) | f2bf(a[2]);
  o.z = ((unsigned)f2bf(a[5]) << 16) | f2bf(a[4]);
  o.w = ((unsigned)f2bf(a[7]) << 16) | f2bf(a[6]);
  *(uint4*)(out + (size_t)w * HD + lane * 8) = o;
}

// ---------------- fused GEMM v4: 256x256 tile, BK=64, counted-vmcnt pipeline (T3+T4+T5)
// 512 threads, 8 waves (2M x 4N), per-wave 128x64, acc[8][4]. LDS 128KB dbuf.
// Raw s_barrier + s_waitcnt vmcnt(8): staging loads stay in flight across barriers.
__global__ __launch_bounds__(512, 2) void gemm_kernel(
    const unsigned short* __restrict__ A0, const unsigned short* __restrict__ A1,
    const unsigned short* __restrict__ Wt, const float* __restrict__ bias,
    unsigned short* __restrict__ Hout) {
  __shared__ __align__(16) unsigned short Ads[2][256 * 64];
  __shared__ __align__(16) unsigned short Bds[2][256 * 64];

  const int tid = threadIdx.x;
  const int lane = tid & 63;
  const int wv = tid >> 6;   // 0..7
  const int wm = wv >> 2;    // 0..1  (128-row slice)
  const int wn = wv & 3;     // 0..3  (64-col slice)

  // XCD chunk swizzle: 392 = 8*49 exact; nt-pairs of one mt stay on one XCD
  const int orig = blockIdx.x;
  const int wgid = (orig & 7) * 49 + (orig >> 3);
  const int mt = wgid >> 1;        // 0..195
  const int nt = wgid & 1;         // 0..1
  const int row0 = mt * 256;
  const int col0 = nt * 256;

  f32x4 acc[8][4];
#pragma unroll
  for (int i = 0; i < 8; i++)
#pragma unroll
    for (int j = 0; j < 4; j++) acc[i][j] = (f32x4)(0.f);

  // staging: per K-tile, A = 256x64 (4 gloads/thread), B = 256x64 (4 gloads/thread)
  int aoff[4], boff[4];
#pragma unroll
  for (int g = 0; g < 4; g++) {
    int s = g * 512 + tid;
    int srow = s >> 3, sch = s & 7;
    int csw = sch ^ (srow & 7);          // pre-swizzled source chunk (T2 pattern)
    aoff[g] = (row0 + srow) * HD + csw * 8;
    boff[g] = (col0 + srow) * K2 + csw * 8;
  }

  auto STAGE = [&](int kt, int buf) {
    const unsigned short* Asrc = (kt < 8) ? A0 : A1;
    const int ka = (kt * 64) & (HD - 1);
    const int k0 = kt * 64;
#pragma unroll
    for (int g = 0; g < 4; g++)
      g2l16(Asrc + aoff[g] + ka, &Ads[buf][(g * 512 + wv * 64) * 8]);
#pragma unroll
    for (int g = 0; g < 4; g++)
      g2l16(Wt + boff[g] + k0, &Bds[buf][(g * 512 + wv * 64) * 8]);
  };

  auto rdA = [&](int buf, int m, int kk) -> bf16x8 {
    int r = wm * 128 + m * 16 + (lane & 15);
    int ck = (kk * 4 + (lane >> 4)) ^ (r & 7);
    return *(const bf16x8*)&Ads[buf][r * 64 + ck * 8];
  };
  auto rdB = [&](int buf, int n, int kk) -> bf16x8 {
    int r = wn * 64 + n * 16 + (lane & 15);
    int ck = (kk * 4 + (lane >> 4)) ^ (r & 7);
    return *(const bf16x8*)&Bds[buf][r * 64 + ck * 8];
  };

  STAGE(0, 0);
  STAGE(1, 1);
  asm volatile("s_waitcnt vmcnt(8)" ::: "memory");   // K-tile 0 landed (tile 1 in flight)
  __builtin_amdgcn_s_barrier();

  for (int kt = 0; kt < 16; ++kt) {
    const int cur = kt & 1;
    bf16x8 fa0[4][2], fa1[4][2], fb0[2][2], fb1[2][2];
    // ---- P1: read A[mh=0] + B[nh=0]; MFMA quad(0,0)
#pragma unroll
    for (int m = 0; m < 4; m++) { fa0[m][0] = rdA(cur, m, 0); fa0[m][1] = rdA(cur, m, 1); }
#pragma unroll
    for (int n = 0; n < 2; n++) { fb0[n][0] = rdB(cur, n, 0); fb0[n][1] = rdB(cur, n, 1); }
    __builtin_amdgcn_s_setprio(1);
#pragma unroll
    for (int m = 0; m < 4; m++)
#pragma unroll
      for (int n = 0; n < 2; n++) {
        acc[m][n] = __builtin_amdgcn_mfma_f32_16x16x32_bf16(fa0[m][0], fb0[n][0], acc[m][n], 0, 0, 0);
        acc[m][n] = __builtin_amdgcn_mfma_f32_16x16x32_bf16(fa0[m][1], fb0[n][1], acc[m][n], 0, 0, 0);
      }
    __builtin_amdgcn_s_setprio(0);
    // ---- P2: read B[nh=1]; MFMA quad(0,1)
#pragma unroll
    for (int n = 0; n < 2; n++) { fb1[n][0] = rdB(cur, n + 2, 0); fb1[n][1] = rdB(cur, n + 2, 1); }
    __builtin_amdgcn_s_setprio(1);
#pragma unroll
    for (int m = 0; m < 4; m++)
#pragma unroll
      for (int n = 0; n < 2; n++) {
        acc[m][n + 2] = __builtin_amdgcn_mfma_f32_16x16x32_bf16(fa0[m][0], fb1[n][0], acc[m][n + 2], 0, 0, 0);
        acc[m][n + 2] = __builtin_amdgcn_mfma_f32_16x16x32_bf16(fa0[m][1], fb1[n][1], acc[m][n + 2], 0, 0, 0);
      }
    __builtin_amdgcn_s_setprio(0);
    // ---- P3: read A[mh=1]; MFMA quad(1,1)
#pragma unroll
    for (int m = 0; m < 4; m++) { fa1[m][0] = rdA(cur, m + 4, 0); fa1[m][1] = rdA(cur, m + 4, 1); }
    __builtin_amdgcn_s_setprio(1);
#pragma unroll
    for (int m = 0; m < 4; m++)
#pragma unroll
      for (int n = 0; n < 2; n++) {
        acc[m + 4][n + 2] = __builtin_amdgcn_mfma_f32_16x16x32_bf16(fa1[m][0], fb1[n][0], acc[m + 4][n + 2], 0, 0, 0);
        acc[m + 4][n + 2] = __builtin_amdgcn_mfma_f32_16x16x32_bf16(fa1[m][1], fb1[n][1], acc[m + 4][n + 2], 0, 0, 0);
      }
    __builtin_amdgcn_s_setprio(0);
    __builtin_amdgcn_s_barrier();   // all waves done reading buf[cur]
    // ---- P4: stage kt+2 into freed buf[cur]; MFMA quad(1,0); counted vmcnt
    if (kt < 14) STAGE(kt + 2, cur);
    __builtin_amdgcn_s_setprio(1);
#pragma unroll
    for (int m = 0; m < 4; m++)
#pragma unroll
      for (int n = 0; n < 2; n++) {
        acc[m + 4][n] = __builtin_amdgcn_mfma_f32_16x16x32_bf16(fa1[m][0], fb0[n][0], acc[m + 4][n], 0, 0, 0);
        acc[m + 4][n] = __builtin_amdgcn_mfma_f32_16x16x32_bf16(fa1[m][1], fb0[n][1], acc[m + 4][n], 0, 0, 0);
      }
    __builtin_amdgcn_s_setprio(0);
    if (kt < 14) {
      asm volatile("s_waitcnt vmcnt(8)" ::: "memory");  // kt+1's 8 loads landed; kt+2 in flight
    } else {
      asm volatile("s_waitcnt vmcnt(0)" ::: "memory");  // drain tail
    }
    __builtin_amdgcn_s_barrier();
  }

#pragma unroll
  for (int n = 0; n < 4; n++) {
    int c = col0 + wn * 64 + n * 16 + (lane & 15);
    float bv = bias[c];
#pragma unroll
    for (int m = 0; m < 8; m++) {
      int rbase = row0 + wm * 128 + m * 16 + (lane >> 4) * 4;
#pragma unroll
      for (int r = 0; r < 4; r++) {
        float v = acc[m][n][r] + bv;
        v = v > 0.f ? v : 0.f;
        Hout[(size_t)(rbase + r) * HD + c] = f2bf(v);
      }
    }
  }
}

// ---------------- mean-pool partial sums (batch is sorted; binary search boundaries)
__device__ __forceinline__ int lbound(const int* b, int v) {
  int lo = 0, hi = NN;
  while (lo < hi) { int m = (lo + hi) >> 1; if (b[m] < v) lo = m + 1; else hi = m; }
  return lo;
}

__global__ void pool_kernel(const unsigned short* __restrict__ H, const int* __restrict__ batch,
                            float* __restrict__ pooled) {
  int b = blockIdx.x;          // 64 graphs * 2 col-halves * 8 row-chunks
  int g = b >> 4;
  int half = (b >> 3) & 1;
  int chunk = b & 7;
  int col = half * 256 + threadIdx.x;
  int start = lbound(batch, g);
  int end = lbound(batch, g + 1);
  int len = end - start;
  int r0 = start + (int)(((long long)len * chunk) >> 3);
  int r1 = start + (int)(((long long)len * (chunk + 1)) >> 3);
  float s = 0.f;
  for (int r = r0; r < r1; r++) s += bf2f(H[(size_t)r * HD + col]);
  atomicAdd(&pooled[g * HD + col], s);
}

// ---------------- classifier: out[g][c] = relu(pooled/cnt) @ Wl + bl
__global__ void final_kernel(const float* __restrict__ pooled, const int* __restrict__ batch,
                             const float* __restrict__ Wl, const float* __restrict__ bl,
                             float* __restrict__ out) {
  int g = blockIdx.x;
  int t = threadIdx.x;   // 256
  int lane = t & 63, wv = t >> 6;
  int start = lbound(batch, g);
  int end = lbound(batch, g + 1);
  float cnt = (float)(end - start);
  if (cnt < 1.f) cnt = 1.f;
  float a[10];
#pragma unroll
  for (int c = 0; c < 10; c++) a[c] = 0.f;
  for (int n = t; n < HD; n += 256) {
    float p = pooled[g * HD + n] / cnt;
    p = p > 0.f ? p : 0.f;
#pragma unroll
    for (int c = 0; c < 10; c++) a[c] += p * Wl[n * 10 + c];
  }
  __shared__ float red[10][4];
#pragma unroll
  for (int c = 0; c < 10; c++) {
    float v = a[c];
#pragma unroll
    for (int off = 32; off >= 1; off >>= 1) v += __shfl_down(v, off);
    if (lane == 0) red[c][wv] = v;
  }
  __syncthreads();
  if (t < 10) out[g * 10 + t] = red[t][0] + red[t][1] + red[t][2] + red[t][3] + bl[t];
}

extern "C" void kernel_launch(void* const* d_in, const int* in_sizes, int n_in,
                              void* d_out, int out_size, void* d_ws, size_t ws_size,
                              hipStream_t stream) {
  const float* x   = (const float*)d_in[0];
  const int* ei    = (const int*)d_in[1];
  const int* batch = (const int*)d_in[2];
  const float* Wr0 = (const float*)d_in[3];
  const float* br0 = (const float*)d_in[4];
  const float* Ws0 = (const float*)d_in[5];
  const float* Wr1 = (const float*)d_in[6];
  const float* br1 = (const float*)d_in[7];
  const float* Ws1 = (const float*)d_in[8];
  const float* Wl  = (const float*)d_in[9];
  const float* bl  = (const float*)d_in[10];
  float* out = (float*)d_out;

  char* ws = (char*)d_ws;
  size_t off = 0;
  auto alloc = [&](size_t bytes) { char* p = ws + off; off += (bytes + 255) & ~255ULL; return p; };
  unsigned short* xb   = (unsigned short*)alloc((size_t)MP * HD * 2);
  unsigned short* h0   = (unsigned short*)alloc((size_t)MP * HD * 2);
  unsigned short* aggb = (unsigned short*)alloc((size_t)MP * HD * 2);
  unsigned short* Wt0  = (unsigned short*)alloc((size_t)HD * K2 * 2);
  unsigned short* Wt1  = (unsigned short*)alloc((size_t)HD * K2 * 2);
  float* pooled        = (float*)alloc((size_t)GG * HD * 4);
  int* deg             = (int*)alloc((size_t)NN * 4);
  int* row_ptr         = (int*)alloc((size_t)(NN + 1) * 4);
  int* cursor          = (int*)alloc((size_t)NN * 4);
  int* col             = (int*)alloc((size_t)NE * 4);
  int* stmp            = (int*)alloc((size_t)NN * 4);
  int* bsum            = (int*)alloc((size_t)256 * 4);
  unsigned short* h1 = xb;  // reuse: xb dead after GEMM0 consumes it

  // init
  hipMemsetAsync(deg, 0, (size_t)NN * 4, stream);
  hipMemsetAsync(pooled, 0, (size_t)GG * HD * 4, stream);

  // fused prologue: wt transpose x2 + cvtpad + hist
  prep_kernel<<<2816, 256, 0, stream>>>(x, xb, Wr0, Ws0, Wt0, Wr1, Ws1, Wt1, ei, deg);

  // CSR scan + fill
  scan1_kernel<<<SCAN_BLKS, 256, 0, stream>>>(deg, stmp, bsum);
  scan2_kernel<<<1, 256, 0, stream>>>(bsum, row_ptr);
  scan3_kernel<<<SCAN_BLKS, 256, 0, stream>>>(stmp, bsum, row_ptr, cursor);
  fill_kernel<<<(NE + 255) / 256, 256, 0, stream>>>(ei, cursor, col);

  // layer 0
  gather_kernel<<<MP / 4, 256, 0, stream>>>(xb, row_ptr, col, aggb);
  gemm_kernel<<<392, 512, 0, stream>>>(aggb, xb, Wt0, br0, h0);

  // layer 1
  gather_kernel<<<MP / 4, 256, 0, stream>>>(h0, row_ptr, col, aggb);
  gemm_kernel<<<392, 512, 0, stream>>>(aggb, h0, Wt1, br1, h1);

  // pool + classify
  pool_kernel<<<GG * 16, 256, 0, stream>>>(h1, batch, pooled);
  final_kernel<<<GG, 256, 0, stream>>>(pooled, batch, Wl, bl, out);
}